// Round 5
// baseline (315.173 us; speedup 1.0000x reference)
//
#include <hip/hip_runtime.h>
#include <math.h>

#define EMB_K   768
#define NH      96
#define SEQLEN  2048
#define NBATCH  16
#define MROWS   (NBATCH * SEQLEN)   // 32768

typedef __bf16 v8bf __attribute__((ext_vector_type(8)));
typedef float  v4f  __attribute__((ext_vector_type(4)));

// ---------------------------------------------------------------------------
// Pack Wq/Wk/Wv (fp32 [768][96]) into bf16 B-fragment order for
// mfma_f32_16x16x32_bf16:  B[k][n], n = lane&15, k = (lane>>4)*8 + e.
// Frag (w, s, j) at ((w*24 + s)*6 + j)*512 + lane*8 + e  (bf16 units)
// ---------------------------------------------------------------------------
__global__ __launch_bounds__(256) void pack_w(
    const float* __restrict__ Wq,
    const float* __restrict__ Wk,
    const float* __restrict__ Wv,
    __bf16* __restrict__ Wp)
{
    int t = blockIdx.x * 256 + threadIdx.x;
    if (t >= 3 * 24 * 6 * 64) return;
    int l  = t & 63;
    int fj = (t >> 6) % 6;
    int s  = ((t >> 6) / 6) % 24;
    int w  = (t >> 6) / (6 * 24);
    const float* W = (w == 0) ? Wq : ((w == 1) ? Wk : Wv);
    int n     = fj * 16 + (l & 15);
    int kbase = s * 32 + (l >> 4) * 8;
    __bf16 o[8];
    #pragma unroll
    for (int e = 0; e < 8; ++e)
        o[e] = (__bf16)W[(size_t)(kbase + e) * NH + n];
    *(v8bf*)(Wp + (size_t)t * 8) = *(v8bf*)o;
}

__device__ inline v8bf cvt8(const float4& a, const float4& b)
{
    v8bf r;
    r[0] = (__bf16)a.x; r[1] = (__bf16)a.y; r[2] = (__bf16)a.z; r[3] = (__bf16)a.w;
    r[4] = (__bf16)b.x; r[5] = (__bf16)b.y; r[6] = (__bf16)b.z; r[7] = (__bf16)b.w;
    return r;
}

// ---------------------------------------------------------------------------
// Fused QKV, split-K. Block = 512 thr = 8 waves = 4 row-tiles x 2 K-halves.
// (unchanged this round)
// ---------------------------------------------------------------------------
__global__ __launch_bounds__(512, 4) void qkv_fused(
    const float* __restrict__ x,
    const __bf16* __restrict__ Wp,
    __bf16* __restrict__ qk,
    __bf16* __restrict__ vt)
{
    __shared__ float  Cs[4][64][25];
    __shared__ __bf16 VsT[96][72];

    const int wave = threadIdx.x >> 6;
    const int p    = wave >> 1;
    const int h    = wave & 1;
    const int lane = threadIdx.x & 63;
    const int mlow = lane & 15;
    const int kq   = lane >> 4;
    const int m0   = blockIdx.x * 64;
    const int r0   = m0 + p * 16;

    const float* xr = x + (size_t)(r0 + mlow) * EMB_K + h * 384 + kq * 8;
    const __bf16* bp = Wp + (size_t)lane * 8;

    v4f acc[3][6];
    #pragma unroll
    for (int w = 0; w < 3; ++w)
        #pragma unroll
        for (int j = 0; j < 6; ++j)
            acc[w][j] = (v4f)0.0f;

    #pragma unroll
    for (int s = 0; s < 12; ++s) {
        float4 lo = *(const float4*)(xr + s * 32);
        float4 hi = *(const float4*)(xr + s * 32 + 4);
        v8bf a = cvt8(lo, hi);
        const int sg = h * 12 + s;
        #pragma unroll
        for (int w = 0; w < 3; ++w)
            #pragma unroll
            for (int j = 0; j < 6; ++j) {
                v8bf bf = *(const v8bf*)(bp + ((size_t)(w * 24 + sg) * 6 + j) * 512);
                acc[w][j] = __builtin_amdgcn_mfma_f32_16x16x32_bf16(a, bf, acc[w][j], 0, 0, 0);
            }
    }

    #pragma unroll
    for (int w = 0; w < 3; ++w) {
        if (h == 1) {
            #pragma unroll
            for (int j = 0; j < 6; ++j)
                #pragma unroll
                for (int r = 0; r < 4; ++r)
                    Cs[p][lane][j * 4 + r] = acc[w][j][r];
        }
        __syncthreads();
        if (h == 0) {
            #pragma unroll
            for (int j = 0; j < 6; ++j)
                #pragma unroll
                for (int r = 0; r < 4; ++r)
                    acc[w][j][r] += Cs[p][lane][j * 4 + r];
        }
        __syncthreads();
    }

    if (h == 0) {
        #pragma unroll
        for (int w = 0; w < 2; ++w) {
            __bf16* op = qk + (size_t)w * MROWS * NH;
            #pragma unroll
            for (int j = 0; j < 6; ++j)
                #pragma unroll
                for (int r = 0; r < 4; ++r)
                    op[(size_t)(r0 + kq * 4 + r) * NH + j * 16 + mlow] = (__bf16)acc[w][j][r];
        }
        #pragma unroll
        for (int j = 0; j < 6; ++j)
            #pragma unroll
            for (int r = 0; r < 4; ++r)
                VsT[j * 16 + mlow][p * 16 + kq * 4 + r] = (__bf16)acc[2][j][r];
    }
    __syncthreads();
    #pragma unroll
    for (int it = 0; it < 2; ++it) {
        int idx = it * 512 + threadIdx.x;
        if (idx < 768) {
            int c = idx >> 3, g = idx & 7;
            *(v8bf*)(vt + (size_t)c * MROWS + m0 + g * 8) = *(const v8bf*)&VsT[c][g * 8];
        }
    }
}

// ---------------------------------------------------------------------------
// MFMA causal flash attention, split-KV.
// FIX vs round 4: the t4 sub-tile loop is now a compile-time 4-iteration
// unroll (always compute all 4 sub-tiles; causal mask applied afterwards on
// the diagonal tile only). Round-4's runtime-bounded loop dynamically indexed
// s2[t4][...] -> compiler demoted s2/pv to scratch (private VMEM) -> ~16k
// cycles per tile iteration. Static subscripts keep everything in VGPRs.
// ---------------------------------------------------------------------------
__global__ __launch_bounds__(256) void attn_mfma(
    const __bf16* __restrict__ qk,
    const __bf16* __restrict__ vt,
    float* __restrict__ out,
    float* __restrict__ Opart,
    float* __restrict__ ml)
{
    __shared__ __bf16 Ps[4][16][72];

    const int bid = blockIdx.x;
    const int b   = bid & 15;
    const int j   = bid >> 4;          // 0..47
    int qt, c0, nch;
    if (j < 16)      { qt = 16 + j;  c0 = 0; nch = 2; }
    else if (j < 32) { qt = 47 - j;  c0 = 1; nch = 2; }
    else             { qt = 47 - j;  c0 = 0; nch = 1; }
    const int t0 = c0 * 16;
    const int t1 = (t0 + 16 < qt + 1) ? (t0 + 16) : (qt + 1);
    const int q0 = qt * 64;

    const int wave = threadIdx.x >> 6;
    const int lane = threadIdx.x & 63;
    const int mlow = lane & 15;
    const int kq   = lane >> 4;

    const __bf16* qp  = qk + (size_t)b * SEQLEN * NH;
    const __bf16* kp  = qk + (size_t)MROWS * NH + (size_t)b * SEQLEN * NH;
    const __bf16* vtp = vt + (size_t)b * SEQLEN;

    const int qrow = q0 + wave * 16 + mlow;
    v8bf qa[3];
    #pragma unroll
    for (int s = 0; s < 3; ++s)
        qa[s] = *(const v8bf*)(qp + (size_t)qrow * NH + s * 32 + kq * 8);

    float m_run[4], l_run[4];
    v4f O[6];
    #pragma unroll
    for (int r = 0; r < 4; ++r) { m_run[r] = -INFINITY; l_run[r] = 0.0f; }
    #pragma unroll
    for (int jj = 0; jj < 6; ++jj) O[jj] = (v4f)0.0f;

    const float sscale = 0.10206207261596575f * 1.4426950408889634f;

    // prefetch first tile's t4=0 K trio
    v8bf k0f[3];
    {
        const __bf16* kr = kp + (size_t)(t0 * 64 + mlow) * NH + kq * 8;
        #pragma unroll
        for (int s = 0; s < 3; ++s) k0f[s] = *(const v8bf*)(kr + s * 32);
    }

    for (int t = t0; t < t1; ++t) {
        const int k0 = t * 64;

        float s2[4][4];
        {   // t4 = 0 from prefetched regs
            v4f sa = (v4f)0.0f;
            #pragma unroll
            for (int s = 0; s < 3; ++s)
                sa = __builtin_amdgcn_mfma_f32_16x16x32_bf16(qa[s], k0f[s], sa, 0, 0, 0);
            #pragma unroll
            for (int r = 0; r < 4; ++r) s2[0][r] = sa[r] * sscale;
        }
        #pragma unroll
        for (int t4 = 1; t4 < 4; ++t4) {   // compile-time trip count: regs stay VGPR
            v4f sa = (v4f)0.0f;
            const __bf16* kr = kp + (size_t)(k0 + t4 * 16 + mlow) * NH + kq * 8;
            #pragma unroll
            for (int s = 0; s < 3; ++s) {
                v8bf kb = *(const v8bf*)(kr + s * 32);
                sa = __builtin_amdgcn_mfma_f32_16x16x32_bf16(qa[s], kb, sa, 0, 0, 0);
            }
            #pragma unroll
            for (int r = 0; r < 4; ++r) s2[t4][r] = sa[r] * sscale;
        }
        // prefetch next tile's t4=0 trio
        if (t + 1 < t1) {
            const __bf16* kr = kp + (size_t)((t + 1) * 64 + mlow) * NH + kq * 8;
            #pragma unroll
            for (int s = 0; s < 3; ++s) k0f[s] = *(const v8bf*)(kr + s * 32);
        }
        // causal mask, diagonal tile only (predicated, no dynamic indexing)
        if (t == qt) {
            #pragma unroll
            for (int t4 = 0; t4 < 4; ++t4)
                #pragma unroll
                for (int r = 0; r < 4; ++r)
                    if (t4 * 16 + mlow > wave * 16 + kq * 4 + r)
                        s2[t4][r] = -1e20f;
        }

        // online softmax
        float mt[4];
        #pragma unroll
        for (int r = 0; r < 4; ++r)
            mt[r] = fmaxf(fmaxf(s2[0][r], s2[1][r]), fmaxf(s2[2][r], s2[3][r]));
        #pragma unroll
        for (int off = 1; off < 16; off <<= 1)
            #pragma unroll
            for (int r = 0; r < 4; ++r)
                mt[r] = fmaxf(mt[r], __shfl_xor(mt[r], off));

        float alpha[4];
        #pragma unroll
        for (int r = 0; r < 4; ++r) {
            float mn = fmaxf(m_run[r], mt[r]);
            alpha[r] = exp2f(m_run[r] - mn);
            m_run[r] = mn;
        }

        float pv[4][4], rs[4];
        #pragma unroll
        for (int r = 0; r < 4; ++r) rs[r] = 0.0f;
        #pragma unroll
        for (int t4 = 0; t4 < 4; ++t4)
            #pragma unroll
            for (int r = 0; r < 4; ++r) {
                pv[t4][r] = exp2f(s2[t4][r] - m_run[r]);
                rs[r] += pv[t4][r];
            }
        #pragma unroll
        for (int off = 1; off < 16; off <<= 1)
            #pragma unroll
            for (int r = 0; r < 4; ++r)
                rs[r] += __shfl_xor(rs[r], off);
        #pragma unroll
        for (int r = 0; r < 4; ++r)
            l_run[r] = l_run[r] * alpha[r] + rs[r];
        #pragma unroll
        for (int jj = 0; jj < 6; ++jj) {
            v4f a4; a4[0]=alpha[0]; a4[1]=alpha[1]; a4[2]=alpha[2]; a4[3]=alpha[3];
            O[jj] *= a4;
        }

        // P: C layout -> per-wave LDS -> A layout
        #pragma unroll
        for (int t4 = 0; t4 < 4; ++t4)
            #pragma unroll
            for (int r = 0; r < 4; ++r)
                Ps[wave][kq * 4 + r][t4 * 16 + mlow] = (__bf16)pv[t4][r];

        v8bf pa0 = *(const v8bf*)&Ps[wave][mlow][kq * 8];
        v8bf pa1 = *(const v8bf*)&Ps[wave][mlow][32 + kq * 8];

        const __bf16* vr = vtp + k0 + kq * 8;
        #pragma unroll
        for (int jj = 0; jj < 6; ++jj) {
            v8bf vb0 = *(const v8bf*)(vr + (size_t)(jj * 16 + mlow) * MROWS);
            v8bf vb1 = *(const v8bf*)(vr + (size_t)(jj * 16 + mlow) * MROWS + 32);
            O[jj] = __builtin_amdgcn_mfma_f32_16x16x32_bf16(pa0, vb0, O[jj], 0, 0, 0);
            O[jj] = __builtin_amdgcn_mfma_f32_16x16x32_bf16(pa1, vb1, O[jj], 0, 0, 0);
        }
    }

    float inv[4];
    #pragma unroll
    for (int r = 0; r < 4; ++r) inv[r] = 1.0f / l_run[r];

    if (nch == 1) {
        #pragma unroll
        for (int r = 0; r < 4; ++r) {
            float* orow = out + ((size_t)b * SEQLEN + q0 + wave * 16 + kq * 4 + r) * NH;
            #pragma unroll
            for (int jj = 0; jj < 6; ++jj)
                orow[jj * 16 + mlow] = O[jj][r] * inv[r];
        }
    } else {
        const int e = (b * 16 + (qt - 16)) * 2 + c0;
        float* Pp = Opart + (size_t)e * 64 * 96;
        #pragma unroll
        for (int r = 0; r < 4; ++r) {
            int row = wave * 16 + kq * 4 + r;
            #pragma unroll
            for (int jj = 0; jj < 6; ++jj)
                Pp[row * 96 + jj * 16 + mlow] = O[jj][r] * inv[r];
            if (mlow == 0) {
                ml[(size_t)e * 128 + row * 2]     = m_run[r];
                ml[(size_t)e * 128 + row * 2 + 1] = l_run[r];
            }
        }
    }
}

// ---------------------------------------------------------------------------
// Merge the two partials for qt>=16 rows. One block per (b, qt).
// ---------------------------------------------------------------------------
__global__ __launch_bounds__(256) void attn_combine(
    const float* __restrict__ Opart,
    const float* __restrict__ ml,
    float* __restrict__ out)
{
    __shared__ float c0s[64], c1s[64];
    const int b  = blockIdx.x & 15;
    const int qr = blockIdx.x >> 4;
    const int e0 = (b * 16 + qr) * 2;
    const int tid = threadIdx.x;
    if (tid < 64) {
        float m0 = ml[(size_t)e0 * 128 + tid * 2];
        float l0 = ml[(size_t)e0 * 128 + tid * 2 + 1];
        float m1 = ml[(size_t)(e0 + 1) * 128 + tid * 2];
        float l1 = ml[(size_t)(e0 + 1) * 128 + tid * 2 + 1];
        float M  = fmaxf(m0, m1);
        float a0 = exp2f(m0 - M) * l0;
        float a1 = exp2f(m1 - M) * l1;
        float inv = 1.0f / (a0 + a1);
        c0s[tid] = a0 * inv;
        c1s[tid] = a1 * inv;
    }
    __syncthreads();
    const float4* P0 = (const float4*)(Opart + (size_t)e0 * 64 * 96);
    const float4* P1 = (const float4*)(Opart + (size_t)(e0 + 1) * 64 * 96);
    float4* op = (float4*)(out + ((size_t)b * SEQLEN + (16 + qr) * 64) * NH);
    #pragma unroll
    for (int it = 0; it < 6; ++it) {
        int idx = it * 256 + tid;
        int row = idx / 24;
        float4 a = P0[idx], c = P1[idx];
        float w0 = c0s[row], w1 = c1s[row];
        float4 o;
        o.x = w0 * a.x + w1 * c.x;
        o.y = w0 * a.y + w1 * c.y;
        o.z = w0 * a.z + w1 * c.z;
        o.w = w0 * a.w + w1 * c.w;
        op[idx] = o;
    }
}

// ---------------------------------------------------------------------------
extern "C" void kernel_launch(void* const* d_in, const int* in_sizes, int n_in,
                              void* d_out, int out_size, void* d_ws, size_t ws_size,
                              hipStream_t stream)
{
    (void)in_sizes; (void)n_in; (void)out_size; (void)ws_size;
    const float* x  = (const float*)d_in[0];
    const float* Wq = (const float*)d_in[1];
    const float* Wk = (const float*)d_in[2];
    const float* Wv = (const float*)d_in[3];
    float* out = (float*)d_out;

    __bf16* qk = (__bf16*)d_ws;                                   // 12.58 MB
    __bf16* vt = qk + (size_t)2 * MROWS * NH;                     //  6.29 MB
    __bf16* Wp = vt + (size_t)NH * MROWS;                         //  0.44 MB
    float* Opart = (float*)(Wp + (size_t)3 * 24 * 6 * 512);       // 12.58 MB
    float* ml    = Opart + (size_t)512 * 64 * 96;                 //  0.26 MB

    pack_w<<<(3 * 24 * 6 * 64 + 255) / 256, 256, 0, stream>>>(Wq, Wk, Wv, Wp);
    qkv_fused<<<MROWS / 64, 512, 0, stream>>>(x, Wp, qk, vt);
    attn_mfma<<<dim3(768), 256, 0, stream>>>(qk, vt, out, Opart, ml);
    attn_combine<<<dim3(256), 256, 0, stream>>>(Opart, ml, out);
}